// Round 12
// baseline (60.008 us; speedup 1.0000x reference)
//
#include <hip/hip_runtime.h>
#include <hip/hip_bf16.h>
#include <utility>

#define DEV static __device__ __forceinline__

typedef __attribute__((ext_vector_type(8))) short bf16x8;
typedef __attribute__((ext_vector_type(4))) float f32x4;

constexpr int KM   = 165;          // number of monomials (deg<=3, 8 complex vars)
constexpr int IT   = 11;           // live i-tiles of 16 (165 -> 176)
constexpr int ITP  = 12;           // padded i-tile count (B layout only)
constexpr int KS   = 6;            // k-steps of 32 -> 192 padded
constexpr int NB   = ITP * KS * 64;
constexpr int ROWS = 64;           // batch rows per block

// ---------------- compile-time POWERS table (itertools.product order) ----------------
struct Pw { unsigned char p[8]; };
struct PwTab { Pw a[KM]; };
constexpr PwTab gen_powers() {
  PwTab t{};
  int idx = 0;
  for (int a0 = 0; a0 <= 3; ++a0)
  for (int a1 = 0; a1 <= 3-a0; ++a1)
  for (int a2 = 0; a2 <= 3-a0-a1; ++a2)
  for (int a3 = 0; a3 <= 3-a0-a1-a2; ++a3)
  for (int a4 = 0; a4 <= 3-a0-a1-a2-a3; ++a4)
  for (int a5 = 0; a5 <= 3-a0-a1-a2-a3-a4; ++a5)
  for (int a6 = 0; a6 <= 3-a0-a1-a2-a3-a4-a5; ++a6)
  for (int a7 = 0; a7 <= 3-a0-a1-a2-a3-a4-a5-a6; ++a7) {
    t.a[idx].p[0] = (unsigned char)a0; t.a[idx].p[1] = (unsigned char)a1;
    t.a[idx].p[2] = (unsigned char)a2; t.a[idx].p[3] = (unsigned char)a3;
    t.a[idx].p[4] = (unsigned char)a4; t.a[idx].p[5] = (unsigned char)a5;
    t.a[idx].p[6] = (unsigned char)a6; t.a[idx].p[7] = (unsigned char)a7;
    ++idx;
  }
  return t;
}
constexpr PwTab PW = gen_powers();

// ---------------- helpers ----------------
DEV unsigned int f2bf(float f) {            // RNE float -> bf16 bits (prep path)
  unsigned int u = __builtin_bit_cast(unsigned int, f);
  u += 0x7fffu + ((u >> 16) & 1u);
  return u >> 16;
}
DEV unsigned int pack2_bits(float lo, float hi) { return f2bf(lo) | (f2bf(hi) << 16); }
// single-instruction packed conversion (gen hot path)
DEV unsigned int pack2(float lo, float hi) {
  unsigned int r;
  asm("v_cvt_pk_bf16_f32 %0, %1, %2" : "=v"(r) : "v"(lo), "v"(hi));
  return r;
}
DEV float softplusf(float x) { return (x > 20.f) ? x : log1pf(expf(x)); }

// ---- monomial evaluation: ALL table indices are template params (scratch-proof) ----
template<int JJ, int C>
DEV void mono_step(float& r, float& i,
                   const float (&lx)[8][3], const float (&ly)[8][3]) {
  constexpr int pc = PW.a[JJ].p[C];
  if constexpr (pc > 0) {
    const float ar = lx[C][pc-1], ai = ly[C][pc-1];
    const float tr = r*ar - i*ai;
    i = r*ai + i*ar;
    r = tr;
  }
}
template<int JJ>
DEV void mono_eval(float& mr, float& mi,
                   const float (&lx)[8][3], const float (&ly)[8][3]) {
  float r = 1.f, i = 0.f;
  mono_step<JJ,0>(r,i,lx,ly); mono_step<JJ,1>(r,i,lx,ly);
  mono_step<JJ,2>(r,i,lx,ly); mono_step<JJ,3>(r,i,lx,ly);
  mono_step<JJ,4>(r,i,lx,ly); mono_step<JJ,5>(r,i,lx,ly);
  mono_step<JJ,6>(r,i,lx,ly); mono_step<JJ,7>(r,i,lx,ly);
  mr = r; mi = i;
}
template<int JJ>
DEV void mono_eval_guard(float& r, float& i,
                         const float (&lx)[8][3], const float (&ly)[8][3]) {
  if constexpr (JJ < KM) mono_eval<JJ>(r, i, lx, ly);
  else { r = 0.f; i = 0.f; }
}

// ---- gen: chunk T covers monomials [8T, 8T+8) = k-slice (ks=T>>2, g=T&3) ----
template<int T, int... Us>
DEV void gen8(std::integer_sequence<int, Us...>, float (&mr)[8], float (&mi)[8],
              const float (&lx)[8][3], const float (&ly)[8][3]) {
  (mono_eval_guard<8*T + Us>(mr[Us], mi[Us], lx, ly), ...);
}
template<int T>
DEV void gen_chunk(const float (&lx)[8][3], const float (&ly)[8][3],
                   unsigned int* Xf, unsigned int* Yf, int mf, int r15) {
  constexpr int ksv = T >> 2;
  constexpr int gv  = T & 3;
  float mr[8], mi[8];
  gen8<T>(std::make_integer_sequence<int, 8>{}, mr, mi, lx, ly);
  uint4 ux, uy;
  ux.x = pack2(mr[0], mr[1]); ux.y = pack2(mr[2], mr[3]);
  ux.z = pack2(mr[4], mr[5]); ux.w = pack2(mr[6], mr[7]);
  uy.x = pack2(mi[0], mi[1]); uy.y = pack2(mi[2], mi[3]);
  uy.z = pack2(mi[4], mi[5]); uy.w = pack2(mi[6], mi[7]);
  const unsigned int off = (unsigned int)((mf*6 + ksv)*256 + gv*64 + r15*4);
  *(uint4*)&Xf[off] = ux;
  *(uint4*)&Yf[off] = uy;
}
template<int W, int... Ts>
DEV void gen_seq(std::integer_sequence<int, Ts...>,
                 const float (&lx)[8][3], const float (&ly)[8][3],
                 unsigned int* Xf, unsigned int* Yf, int mf, int r15) {
  (gen_chunk<6*W + Ts>(lx, ly, Xf, Yf, mf, r15), ...);
}
template<int W>
DEV void gen_wave(const float (&lx)[8][3], const float (&ly)[8][3],
                  unsigned int* Xf, unsigned int* Yf, int mf, int r15) {
  gen_seq<W>(std::make_integer_sequence<int, 6>{}, lx, ly, Xf, Yf, mf, r15);
}

// ---------------- prep: conj(L)^T -> bf16 B-operand fragments (triangular) ----------
__global__ void __launch_bounds__(256) poskahler_prep(
    const float* __restrict__ Lre, const float* __restrict__ Lim,
    uint4* __restrict__ bp, uint4* __restrict__ bq) {
  const int tid = blockIdx.x * 256 + threadIdx.x;
  if (tid >= NB) return;
  const int lane = tid & 63;
  const int it = (tid >> 6) / KS;
  const int ks = (tid >> 6) % KS;
  const int j  = it * 16 + (lane & 15);
  const int ib = ks * 32 + ((lane >> 4) << 3);
  float pr[8], qr[8];
#pragma unroll
  for (int e = 0; e < 8; ++e) { pr[e] = 0.f; qr[e] = 0.f; }
  if (j < KM) {
#pragma unroll
    for (int e = 0; e < 8; ++e) {
      const int i = ib + e;
      if (i < KM) {
        if (i > j)      { pr[e] = Lre[i*KM + j]; qr[e] = -Lim[i*KM + j]; }
        else if (i == j){ pr[e] = softplusf(Lre[j*KM + j]) + 0.001f; }
      }
    }
  }
  uint4 up, uq;
  up.x = pack2_bits(pr[0], pr[1]); up.y = pack2_bits(pr[2], pr[3]);
  up.z = pack2_bits(pr[4], pr[5]); up.w = pack2_bits(pr[6], pr[7]);
  uq.x = pack2_bits(qr[0], qr[1]); uq.y = pack2_bits(qr[2], qr[3]);
  uq.z = pack2_bits(qr[4], qr[5]); uq.w = pack2_bits(qr[6], qr[7]);
  bp[tid] = up;
  bq[tid] = uq;
}

// ---------------- per-wave k-plans: complete-k i-tiles, balanced 11/11/10/9 ---------
// L^H tile (it,ks) is live iff it <= 2ks+1; every live tile appears exactly once.
struct WQ { int n; signed char it[11]; signed char ks[11]; };
constexpr WQ WQP[4] = {
  {11, {0,0,0,0,0,0, 7,7,7, 8,8},    {0,1,2,3,4,5, 3,4,5, 4,5}},
  {11, {1,1,1,1,1,1, 6,6,6, 9,9},    {0,1,2,3,4,5, 3,4,5, 4,5}},
  {10, {2,2,2,2,2, 4,4,4,4, 10,-1},  {1,2,3,4,5, 2,3,4,5, 5,-1}},
  {9,  {3,3,3,3,3, 5,5,5,5,-1,-1},   {1,2,3,4,5, 2,3,4,5,-1,-1}},
};

template<int W>
DEV void preload(const uint4* __restrict__ bp, const uint4* __restrict__ bq,
                 int lane, uint4 (&tP)[2], uint4 (&tQ)[2]) {
  constexpr int f0 = (WQP[W].it[0]*KS + WQP[W].ks[0]) * 64;
  constexpr int f1 = (WQP[W].it[1]*KS + WQP[W].ks[1]) * 64;
  tP[0] = bp[f0 + lane]; tQ[0] = bq[f0 + lane];
  tP[1] = bp[f1 + lane]; tQ[1] = bq[f1 + lane];
}

template<int W, int I>
DEV void tile_step(const unsigned int* Xf, const unsigned int* Yf,
                   const uint4* __restrict__ bp, const uint4* __restrict__ bq,
                   int lane, uint4 (&tP)[2], uint4 (&tQ)[2],
                   f32x4 (&aRe)[4], f32x4 (&aIm)[4], float (&p)[4][4]) {
  constexpr int ks = WQP[W].ks[I];
  const uint4 up = tP[I & 1];
  const uint4 uq = tQ[I & 1];
  if constexpr (I + 2 < WQP[W].n) {        // distance-2 prefetch into freed slot
    constexpr int fs0 = (WQP[W].it[I+2]*KS + WQP[W].ks[I+2]) * 64;
    tP[I & 1] = bp[fs0 + lane];
    tQ[I & 1] = bq[fs0 + lane];
  }
  uint4 un;
  un.x = uq.x ^ 0x80008000u; un.y = uq.y ^ 0x80008000u;
  un.z = uq.z ^ 0x80008000u; un.w = uq.w ^ 0x80008000u;
  const bf16x8 vp = __builtin_bit_cast(bf16x8, up);
  const bf16x8 vq = __builtin_bit_cast(bf16x8, uq);
  const bf16x8 vn = __builtin_bit_cast(bf16x8, un);
#pragma unroll
  for (int mf = 0; mf < 4; ++mf) {
    const unsigned int off = (unsigned int)((mf*6 + ks)*256) + (unsigned int)lane*4;
    const bf16x8 xf = __builtin_bit_cast(bf16x8, *(const uint4*)&Xf[off]);
    const bf16x8 yf = __builtin_bit_cast(bf16x8, *(const uint4*)&Yf[off]);
    // wre = P x + Q y ; wim = P y - Q x
    aRe[mf] = __builtin_amdgcn_mfma_f32_16x16x32_bf16(xf, vp, aRe[mf], 0, 0, 0);
    aRe[mf] = __builtin_amdgcn_mfma_f32_16x16x32_bf16(yf, vq, aRe[mf], 0, 0, 0);
    aIm[mf] = __builtin_amdgcn_mfma_f32_16x16x32_bf16(yf, vp, aIm[mf], 0, 0, 0);
    aIm[mf] = __builtin_amdgcn_mfma_f32_16x16x32_bf16(xf, vn, aIm[mf], 0, 0, 0);
  }
  // fold |w|^2 when this i-tile's k-range completes (next entry is a new it)
  if constexpr (I + 1 == WQP[W].n || WQP[W].it[I+1] != WQP[W].it[I]) {
#pragma unroll
    for (int mf = 0; mf < 4; ++mf) {
#pragma unroll
      for (int rr = 0; rr < 4; ++rr)
        p[mf][rr] += aRe[mf][rr]*aRe[mf][rr] + aIm[mf][rr]*aIm[mf][rr];
      aRe[mf] = (f32x4){0.f,0.f,0.f,0.f};
      aIm[mf] = (f32x4){0.f,0.f,0.f,0.f};
    }
  }
}

template<int W, int... Is>
DEV void run_tiles(std::integer_sequence<int, Is...>,
                   const unsigned int* Xf, const unsigned int* Yf,
                   const uint4* __restrict__ bp, const uint4* __restrict__ bq,
                   int lane, uint4 (&tP)[2], uint4 (&tQ)[2],
                   f32x4 (&aRe)[4], f32x4 (&aIm)[4], float (&p)[4][4]) {
  (tile_step<W, Is>(Xf, Yf, bp, bq, lane, tP, tQ, aRe, aIm, p), ...);
}
template<int W>
DEV void run_wave(const unsigned int* Xf, const unsigned int* Yf,
                  const uint4* __restrict__ bp, const uint4* __restrict__ bq,
                  int lane, uint4 (&tP)[2], uint4 (&tQ)[2],
                  f32x4 (&aRe)[4], f32x4 (&aIm)[4], float (&p)[4][4]) {
  run_tiles<W>(std::make_integer_sequence<int, WQP[W].n>{},
               Xf, Yf, bp, bq, lane, tP, tQ, aRe, aIm, p);
}

// ---------------- main: monomials -> w = L^H z via MFMA -> log(|w|^2) --------------
__global__ void __launch_bounds__(256, 3) poskahler_main(
    const float* __restrict__ q,
    const uint4* __restrict__ bp, const uint4* __restrict__ bq,
    float* __restrict__ out) {
  // fragment-ordered monomial store: region (mf*6+ks)*256 dwords, lane entry lane*4
  __shared__ __align__(16) unsigned int Xf[6144];
  __shared__ __align__(16) unsigned int Yf[6144];
  __shared__ float qpart[4][ROWS];

  const int t     = threadIdx.x;
  const int lane  = t & 63;
  const int wv    = t >> 6;                 // 4 waves
  const int bbase = blockIdx.x * ROWS;
  const int mf_r  = lane >> 4;              // gen: this thread's row -> frag mf
  const int r15   = lane & 15;

  // ---- q row load FIRST (HBM latency starts draining before everything else) ----
  const float* qr = q + (size_t)(bbase + lane) * 16;
  const float4 q0 = ((const float4*)qr)[0];
  const float4 q1 = ((const float4*)qr)[1];
  const float4 q2 = ((const float4*)qr)[2];
  const float4 q3 = ((const float4*)qr)[3];

  // ---- B-tile preload for plan slots 0,1 (latency hides under gen) ----
  uint4 tP[2], tQ[2];
  switch (wv) {
    case 0: preload<0>(bp, bq, lane, tP, tQ); break;
    case 1: preload<1>(bp, bq, lane, tP, tQ); break;
    case 2: preload<2>(bp, bq, lane, tP, tQ); break;
    default: preload<3>(bp, bq, lane, tP, tQ); break;
  }

  // ---- monomial generation: wave wv covers monomials [48wv, 48wv+48) of each row --
  {
    const float xs[8] = {q0.x,q0.y,q0.z,q0.w,q1.x,q1.y,q1.z,q1.w};
    const float ys[8] = {q2.x,q2.y,q2.z,q2.w,q3.x,q3.y,q3.z,q3.w};
    float lx[8][3], ly[8][3];
#pragma unroll
    for (int c = 0; c < 8; ++c) {
      const float xr = xs[c], yi = ys[c];
      lx[c][0] = xr;             ly[c][0] = yi;
      lx[c][1] = xr*xr - yi*yi;  ly[c][1] = 2.f*xr*yi;
      lx[c][2] = lx[c][1]*xr - ly[c][1]*yi;
      ly[c][2] = lx[c][1]*yi + ly[c][1]*xr;
    }
    switch (wv) {
      case 0: gen_wave<0>(lx, ly, Xf, Yf, mf_r, r15); break;
      case 1: gen_wave<1>(lx, ly, Xf, Yf, mf_r, r15); break;
      case 2: gen_wave<2>(lx, ly, Xf, Yf, mf_r, r15); break;
      default: gen_wave<3>(lx, ly, Xf, Yf, mf_r, r15); break;
    }
  }
  __syncthreads();

  // ---- w = L^H z : per-wave complete-k i-tile jobs, fold |w|^2 per tile ----
  f32x4 aRe[4], aIm[4];
#pragma unroll
  for (int mf = 0; mf < 4; ++mf) {
    aRe[mf] = (f32x4){0.f,0.f,0.f,0.f};
    aIm[mf] = (f32x4){0.f,0.f,0.f,0.f};
  }
  float p[4][4];
#pragma unroll
  for (int mf = 0; mf < 4; ++mf)
#pragma unroll
    for (int rr = 0; rr < 4; ++rr) p[mf][rr] = 0.f;

  switch (wv) {
    case 0: run_wave<0>(Xf, Yf, bp, bq, lane, tP, tQ, aRe, aIm, p); break;
    case 1: run_wave<1>(Xf, Yf, bp, bq, lane, tP, tQ, aRe, aIm, p); break;
    case 2: run_wave<2>(Xf, Yf, bp, bq, lane, tP, tQ, aRe, aIm, p); break;
    default: run_wave<3>(Xf, Yf, bp, bq, lane, tP, tQ, aRe, aIm, p); break;
  }

  // ---- reduce over the 16 j-lanes ----
#pragma unroll
  for (int mf = 0; mf < 4; ++mf)
#pragma unroll
    for (int rr = 0; rr < 4; ++rr) {
      float v = p[mf][rr];
      v += __shfl_xor(v, 1);
      v += __shfl_xor(v, 2);
      v += __shfl_xor(v, 4);
      v += __shfl_xor(v, 8);
      p[mf][rr] = v;
    }

  if (r15 == 0) {
    const int g = lane >> 4;
#pragma unroll
    for (int mf = 0; mf < 4; ++mf)
#pragma unroll
      for (int rr = 0; rr < 4; ++rr)
        qpart[wv][mf*16 + 4*g + rr] = p[mf][rr];
  }
  __syncthreads();
  if (t < ROWS) {
    const float quad = qpart[0][t] + qpart[1][t] + qpart[2][t] + qpart[3][t];
    out[bbase + t] = logf(quad + 1e-12f);
  }
}

// ---------------- host ----------------
extern "C" void kernel_launch(void* const* d_in, const int* in_sizes, int n_in,
                              void* d_out, int out_size, void* d_ws, size_t ws_size,
                              hipStream_t stream) {
  const float* q   = (const float*)d_in[0];
  const float* Lre = (const float*)d_in[1];
  const float* Lim = (const float*)d_in[2];
  float* out = (float*)d_out;
  uint4* bp = (uint4*)d_ws;
  uint4* bq = bp + NB;
  const int B = in_sizes[0] / 16;
  poskahler_prep<<<(NB + 255)/256, 256, 0, stream>>>(Lre, Lim, bp, bq);
  poskahler_main<<<B / ROWS, 256, 0, stream>>>(q, bp, bq, out);
}

// Round 13
// 53.729 us; speedup vs baseline: 1.1169x; 1.1169x over previous
//
#include <hip/hip_runtime.h>
#include <hip/hip_bf16.h>
#include <utility>

#define DEV static __device__ __forceinline__

typedef __attribute__((ext_vector_type(8))) short bf16x8;
typedef __attribute__((ext_vector_type(4))) float f32x4;

constexpr int KM   = 165;          // number of monomials (deg<=3, 8 complex vars)
constexpr int IT   = 11;           // live i-tiles of 16 (165 -> 176)
constexpr int ITP  = 12;           // padded i-tile count (B layout only)
constexpr int KS   = 6;            // k-steps of 32 -> 192 padded
constexpr int NB   = ITP * KS * 64;
constexpr int ROWS = 64;           // batch rows per block

// ---------------- compile-time POWERS table (itertools.product order) ----------------
struct Pw { unsigned char p[8]; };
struct PwTab { Pw a[KM]; };
constexpr PwTab gen_powers() {
  PwTab t{};
  int idx = 0;
  for (int a0 = 0; a0 <= 3; ++a0)
  for (int a1 = 0; a1 <= 3-a0; ++a1)
  for (int a2 = 0; a2 <= 3-a0-a1; ++a2)
  for (int a3 = 0; a3 <= 3-a0-a1-a2; ++a3)
  for (int a4 = 0; a4 <= 3-a0-a1-a2-a3; ++a4)
  for (int a5 = 0; a5 <= 3-a0-a1-a2-a3-a4; ++a5)
  for (int a6 = 0; a6 <= 3-a0-a1-a2-a3-a4-a5; ++a6)
  for (int a7 = 0; a7 <= 3-a0-a1-a2-a3-a4-a5-a6; ++a7) {
    t.a[idx].p[0] = (unsigned char)a0; t.a[idx].p[1] = (unsigned char)a1;
    t.a[idx].p[2] = (unsigned char)a2; t.a[idx].p[3] = (unsigned char)a3;
    t.a[idx].p[4] = (unsigned char)a4; t.a[idx].p[5] = (unsigned char)a5;
    t.a[idx].p[6] = (unsigned char)a6; t.a[idx].p[7] = (unsigned char)a7;
    ++idx;
  }
  return t;
}
constexpr PwTab PW = gen_powers();

// ---------------- helpers ----------------
DEV unsigned int f2bf(float f) {            // RNE float -> bf16 bits (prep path)
  unsigned int u = __builtin_bit_cast(unsigned int, f);
  u += 0x7fffu + ((u >> 16) & 1u);
  return u >> 16;
}
DEV unsigned int pack2_bits(float lo, float hi) { return f2bf(lo) | (f2bf(hi) << 16); }
// single-instruction packed conversion (gen hot path)
DEV unsigned int pack2(float lo, float hi) {
  unsigned int r;
  asm("v_cvt_pk_bf16_f32 %0, %1, %2" : "=v"(r) : "v"(lo), "v"(hi));
  return r;
}
DEV float softplusf(float x) { return (x > 20.f) ? x : log1pf(expf(x)); }

// ---- monomial evaluation: ALL table indices are template params (scratch-proof) ----
template<int JJ, int C>
DEV void mono_step(float& r, float& i,
                   const float (&lx)[8][3], const float (&ly)[8][3]) {
  constexpr int pc = PW.a[JJ].p[C];
  if constexpr (pc > 0) {
    const float ar = lx[C][pc-1], ai = ly[C][pc-1];
    const float tr = r*ar - i*ai;
    i = r*ai + i*ar;
    r = tr;
  }
}
template<int JJ>
DEV void mono_eval(float& mr, float& mi,
                   const float (&lx)[8][3], const float (&ly)[8][3]) {
  float r = 1.f, i = 0.f;
  mono_step<JJ,0>(r,i,lx,ly); mono_step<JJ,1>(r,i,lx,ly);
  mono_step<JJ,2>(r,i,lx,ly); mono_step<JJ,3>(r,i,lx,ly);
  mono_step<JJ,4>(r,i,lx,ly); mono_step<JJ,5>(r,i,lx,ly);
  mono_step<JJ,6>(r,i,lx,ly); mono_step<JJ,7>(r,i,lx,ly);
  mr = r; mi = i;
}
template<int JJ>
DEV void mono_eval_guard(float& r, float& i,
                         const float (&lx)[8][3], const float (&ly)[8][3]) {
  if constexpr (JJ < KM) mono_eval<JJ>(r, i, lx, ly);
  else { r = 0.f; i = 0.f; }
}

// ---- gen: chunk T covers monomials [8T, 8T+8) = k-slice (ks=T>>2, g=T&3) ----
template<int T, int... Us>
DEV void gen8(std::integer_sequence<int, Us...>, float (&mr)[8], float (&mi)[8],
              const float (&lx)[8][3], const float (&ly)[8][3]) {
  (mono_eval_guard<8*T + Us>(mr[Us], mi[Us], lx, ly), ...);
}
template<int T>
DEV void gen_chunk(const float (&lx)[8][3], const float (&ly)[8][3],
                   unsigned int* Xf, unsigned int* Yf, int mf, int r15) {
  constexpr int ksv = T >> 2;
  constexpr int gv  = T & 3;
  float mr[8], mi[8];
  gen8<T>(std::make_integer_sequence<int, 8>{}, mr, mi, lx, ly);
  uint4 ux, uy;
  ux.x = pack2(mr[0], mr[1]); ux.y = pack2(mr[2], mr[3]);
  ux.z = pack2(mr[4], mr[5]); ux.w = pack2(mr[6], mr[7]);
  uy.x = pack2(mi[0], mi[1]); uy.y = pack2(mi[2], mi[3]);
  uy.z = pack2(mi[4], mi[5]); uy.w = pack2(mi[6], mi[7]);
  const unsigned int off = (unsigned int)((mf*6 + ksv)*256 + gv*64 + r15*4);
  *(uint4*)&Xf[off] = ux;
  *(uint4*)&Yf[off] = uy;
}
template<int W, int... Ts>
DEV void gen_seq(std::integer_sequence<int, Ts...>,
                 const float (&lx)[8][3], const float (&ly)[8][3],
                 unsigned int* Xf, unsigned int* Yf, int mf, int r15) {
  (gen_chunk<6*W + Ts>(lx, ly, Xf, Yf, mf, r15), ...);
}
template<int W>
DEV void gen_wave(const float (&lx)[8][3], const float (&ly)[8][3],
                  unsigned int* Xf, unsigned int* Yf, int mf, int r15) {
  gen_seq<W>(std::make_integer_sequence<int, 6>{}, lx, ly, Xf, Yf, mf, r15);
}

// ---------------- prep: conj(L)^T -> bf16 B-operand fragments (triangular) ----------
__global__ void __launch_bounds__(256) poskahler_prep(
    const float* __restrict__ Lre, const float* __restrict__ Lim,
    uint4* __restrict__ bp, uint4* __restrict__ bq) {
  const int tid = blockIdx.x * 256 + threadIdx.x;
  if (tid >= NB) return;
  const int lane = tid & 63;
  const int it = (tid >> 6) / KS;
  const int ks = (tid >> 6) % KS;
  const int j  = it * 16 + (lane & 15);
  const int ib = ks * 32 + ((lane >> 4) << 3);
  float pr[8], qr[8];
#pragma unroll
  for (int e = 0; e < 8; ++e) { pr[e] = 0.f; qr[e] = 0.f; }
  if (j < KM) {
#pragma unroll
    for (int e = 0; e < 8; ++e) {
      const int i = ib + e;
      if (i < KM) {
        if (i > j)      { pr[e] = Lre[i*KM + j]; qr[e] = -Lim[i*KM + j]; }
        else if (i == j){ pr[e] = softplusf(Lre[j*KM + j]) + 0.001f; }
      }
    }
  }
  uint4 up, uq;
  up.x = pack2_bits(pr[0], pr[1]); up.y = pack2_bits(pr[2], pr[3]);
  up.z = pack2_bits(pr[4], pr[5]); up.w = pack2_bits(pr[6], pr[7]);
  uq.x = pack2_bits(qr[0], qr[1]); uq.y = pack2_bits(qr[2], qr[3]);
  uq.z = pack2_bits(qr[4], qr[5]); uq.w = pack2_bits(qr[6], qr[7]);
  bp[tid] = up;
  bq[tid] = uq;
}

// ---------------- main k-loop building blocks (fully static) ----------------
template<int KSv>
DEV void load_tiles(const uint4* __restrict__ bp, const uint4* __restrict__ bq,
                    int wv, int lane, uint4 (&tp)[3], uint4 (&tq)[3]) {
#pragma unroll
  for (int ii = 0; ii < 3; ++ii) {
    const int it = 4*ii + wv;
    if (it <= 2*KSv + 1 && it < IT) {
      const int fs = (it*KS + KSv)*64 + lane;
      tp[ii] = bp[fs];
      tq[ii] = bq[fs];
    }
  }
}

template<int KSv>
DEV void compute_ks(const unsigned int* Xf, const unsigned int* Yf,
                    int wv, int lane,
                    const uint4 (&tp)[3], const uint4 (&tq)[3],
                    float (&aRe)[3][4][4], float (&aIm)[3][4][4]) {
  bf16x8 xf[4], yf[4];
#pragma unroll
  for (int mf = 0; mf < 4; ++mf) {
    const unsigned int off = (unsigned int)((mf*6 + KSv)*256) + (unsigned int)lane*4;
    xf[mf] = __builtin_bit_cast(bf16x8, *(const uint4*)&Xf[off]);
    yf[mf] = __builtin_bit_cast(bf16x8, *(const uint4*)&Yf[off]);
  }
#pragma unroll
  for (int ii = 0; ii < 3; ++ii) {
    const int it = 4*ii + wv;
    if (it <= 2*KSv + 1 && it < IT) {
      const uint4 up = tp[ii];
      const uint4 uq = tq[ii];
      uint4 un;
      un.x = uq.x ^ 0x80008000u; un.y = uq.y ^ 0x80008000u;
      un.z = uq.z ^ 0x80008000u; un.w = uq.w ^ 0x80008000u;
      const bf16x8 vp = __builtin_bit_cast(bf16x8, up);
      const bf16x8 vq = __builtin_bit_cast(bf16x8, uq);
      const bf16x8 vn = __builtin_bit_cast(bf16x8, un);
#pragma unroll
      for (int mf = 0; mf < 4; ++mf) {
        f32x4 cre = { aRe[ii][mf][0], aRe[ii][mf][1], aRe[ii][mf][2], aRe[ii][mf][3] };
        f32x4 cim = { aIm[ii][mf][0], aIm[ii][mf][1], aIm[ii][mf][2], aIm[ii][mf][3] };
        // wre = P x + Q y ; wim = P y - Q x
        cre = __builtin_amdgcn_mfma_f32_16x16x32_bf16(xf[mf], vp, cre, 0, 0, 0);
        cre = __builtin_amdgcn_mfma_f32_16x16x32_bf16(yf[mf], vq, cre, 0, 0, 0);
        cim = __builtin_amdgcn_mfma_f32_16x16x32_bf16(yf[mf], vp, cim, 0, 0, 0);
        cim = __builtin_amdgcn_mfma_f32_16x16x32_bf16(xf[mf], vn, cim, 0, 0, 0);
#pragma unroll
        for (int rr = 0; rr < 4; ++rr) { aRe[ii][mf][rr] = cre[rr]; aIm[ii][mf][rr] = cim[rr]; }
      }
    }
  }
}

// ---------------- main: monomials -> w = L^H z via MFMA -> log(|w|^2) --------------
// Single-buffered B tiles (24 VGPR instead of 48): total regs ~148 < 170 so three
// waves/SIMD fit under __launch_bounds__(256,3) WITHOUT spill (r12 lesson: pool=512).
__global__ void __launch_bounds__(256, 3) poskahler_main(
    const float* __restrict__ q,
    const uint4* __restrict__ bp, const uint4* __restrict__ bq,
    float* __restrict__ out) {
  // fragment-ordered monomial store: region (mf*6+ks)*256 dwords, lane entry lane*4
  __shared__ __align__(16) unsigned int Xf[6144];
  __shared__ __align__(16) unsigned int Yf[6144];
  __shared__ float qpart[4][ROWS];

  const int t     = threadIdx.x;
  const int lane  = t & 63;
  const int wv    = t >> 6;                 // 4 waves
  const int bbase = blockIdx.x * ROWS;
  const int mf_r  = lane >> 4;              // gen: this thread's row -> frag mf
  const int r15   = lane & 15;

  // ---- q row load FIRST (HBM latency starts draining before everything else) ----
  const float* qr = q + (size_t)(bbase + lane) * 16;
  const float4 q0 = ((const float4*)qr)[0];
  const float4 q1 = ((const float4*)qr)[1];
  const float4 q2 = ((const float4*)qr)[2];
  const float4 q3 = ((const float4*)qr)[3];

  // ---- B-tile preload for ks=0 only (single buffer, latency hides under gen) ----
  uint4 tp[3] = {}, tq[3] = {};
  load_tiles<0>(bp, bq, wv, lane, tp, tq);

  // ---- monomial generation: wave wv covers monomials [48wv, 48wv+48) of each row --
  {
    const float xs[8] = {q0.x,q0.y,q0.z,q0.w,q1.x,q1.y,q1.z,q1.w};
    const float ys[8] = {q2.x,q2.y,q2.z,q2.w,q3.x,q3.y,q3.z,q3.w};
    float lx[8][3], ly[8][3];
#pragma unroll
    for (int c = 0; c < 8; ++c) {
      const float xr = xs[c], yi = ys[c];
      lx[c][0] = xr;             ly[c][0] = yi;
      lx[c][1] = xr*xr - yi*yi;  ly[c][1] = 2.f*xr*yi;
      lx[c][2] = lx[c][1]*xr - ly[c][1]*yi;
      ly[c][2] = lx[c][1]*yi + ly[c][1]*xr;
    }
    switch (wv) {
      case 0: gen_wave<0>(lx, ly, Xf, Yf, mf_r, r15); break;
      case 1: gen_wave<1>(lx, ly, Xf, Yf, mf_r, r15); break;
      case 2: gen_wave<2>(lx, ly, Xf, Yf, mf_r, r15); break;
      default: gen_wave<3>(lx, ly, Xf, Yf, mf_r, r15); break;
    }
  }
  __syncthreads();

  // ---- w = L^H z : ks fully unrolled, single-buffered B tiles ----
  float aRe[3][4][4], aIm[3][4][4];
#pragma unroll
  for (int ii = 0; ii < 3; ++ii)
#pragma unroll
    for (int mf = 0; mf < 4; ++mf)
#pragma unroll
      for (int rr = 0; rr < 4; ++rr) { aRe[ii][mf][rr] = 0.f; aIm[ii][mf][rr] = 0.f; }

  compute_ks<0>(Xf, Yf, wv, lane, tp, tq, aRe, aIm);
  load_tiles<1>(bp, bq, wv, lane, tp, tq);
  compute_ks<1>(Xf, Yf, wv, lane, tp, tq, aRe, aIm);
  load_tiles<2>(bp, bq, wv, lane, tp, tq);
  compute_ks<2>(Xf, Yf, wv, lane, tp, tq, aRe, aIm);
  load_tiles<3>(bp, bq, wv, lane, tp, tq);
  compute_ks<3>(Xf, Yf, wv, lane, tp, tq, aRe, aIm);
  load_tiles<4>(bp, bq, wv, lane, tp, tq);
  compute_ks<4>(Xf, Yf, wv, lane, tp, tq, aRe, aIm);
  load_tiles<5>(bp, bq, wv, lane, tp, tq);
  compute_ks<5>(Xf, Yf, wv, lane, tp, tq, aRe, aIm);

  // ---- epilogue: quad partial = sum_j |w_j|^2 ----
  float p[4][4];
#pragma unroll
  for (int mf = 0; mf < 4; ++mf)
#pragma unroll
    for (int rr = 0; rr < 4; ++rr) p[mf][rr] = 0.f;

#pragma unroll
  for (int ii = 0; ii < 3; ++ii)
#pragma unroll
    for (int mf = 0; mf < 4; ++mf)
#pragma unroll
      for (int rr = 0; rr < 4; ++rr)
        p[mf][rr] += aRe[ii][mf][rr]*aRe[ii][mf][rr] + aIm[ii][mf][rr]*aIm[ii][mf][rr];

#pragma unroll
  for (int mf = 0; mf < 4; ++mf)
#pragma unroll
    for (int rr = 0; rr < 4; ++rr) {
      float v = p[mf][rr];
      v += __shfl_xor(v, 1);
      v += __shfl_xor(v, 2);
      v += __shfl_xor(v, 4);
      v += __shfl_xor(v, 8);
      p[mf][rr] = v;
    }

  if (r15 == 0) {
    const int g = lane >> 4;
#pragma unroll
    for (int mf = 0; mf < 4; ++mf)
#pragma unroll
      for (int rr = 0; rr < 4; ++rr)
        qpart[wv][mf*16 + 4*g + rr] = p[mf][rr];
  }
  __syncthreads();
  if (t < ROWS) {
    const float quad = qpart[0][t] + qpart[1][t] + qpart[2][t] + qpart[3][t];
    out[bbase + t] = logf(quad + 1e-12f);
  }
}

// ---------------- host ----------------
extern "C" void kernel_launch(void* const* d_in, const int* in_sizes, int n_in,
                              void* d_out, int out_size, void* d_ws, size_t ws_size,
                              hipStream_t stream) {
  const float* q   = (const float*)d_in[0];
  const float* Lre = (const float*)d_in[1];
  const float* Lim = (const float*)d_in[2];
  float* out = (float*)d_out;
  uint4* bp = (uint4*)d_ws;
  uint4* bq = bp + NB;
  const int B = in_sizes[0] / 16;
  poskahler_prep<<<(NB + 255)/256, 256, 0, stream>>>(Lre, Lim, bp, bq);
  poskahler_main<<<B / ROWS, 256, 0, stream>>>(q, bp, bq, out);
}

// Round 15
// 52.157 us; speedup vs baseline: 1.1505x; 1.0301x over previous
//
#include <hip/hip_runtime.h>
#include <hip/hip_bf16.h>
#include <utility>

#define DEV static __device__ __forceinline__

typedef __attribute__((ext_vector_type(8))) short bf16x8;
typedef __attribute__((ext_vector_type(4))) float f32x4;

constexpr int KM   = 165;          // number of monomials (deg<=3, 8 complex vars)
constexpr int IT   = 11;           // live i-tiles of 16 (165 -> 176)
constexpr int ITP  = 12;           // padded i-tile count (B layout only)
constexpr int KS   = 6;            // k-steps of 32 -> 192 padded
constexpr int NB   = ITP * KS * 64;
constexpr int ROWS = 64;           // batch rows per block

// ---------------- compile-time POWERS table (itertools.product order) ----------------
struct Pw { unsigned char p[8]; };
struct PwTab { Pw a[KM]; };
constexpr PwTab gen_powers() {
  PwTab t{};
  int idx = 0;
  for (int a0 = 0; a0 <= 3; ++a0)
  for (int a1 = 0; a1 <= 3-a0; ++a1)
  for (int a2 = 0; a2 <= 3-a0-a1; ++a2)
  for (int a3 = 0; a3 <= 3-a0-a1-a2; ++a3)
  for (int a4 = 0; a4 <= 3-a0-a1-a2-a3; ++a4)
  for (int a5 = 0; a5 <= 3-a0-a1-a2-a3-a4; ++a5)
  for (int a6 = 0; a6 <= 3-a0-a1-a2-a3-a4-a5; ++a6)
  for (int a7 = 0; a7 <= 3-a0-a1-a2-a3-a4-a5-a6; ++a7) {
    t.a[idx].p[0] = (unsigned char)a0; t.a[idx].p[1] = (unsigned char)a1;
    t.a[idx].p[2] = (unsigned char)a2; t.a[idx].p[3] = (unsigned char)a3;
    t.a[idx].p[4] = (unsigned char)a4; t.a[idx].p[5] = (unsigned char)a5;
    t.a[idx].p[6] = (unsigned char)a6; t.a[idx].p[7] = (unsigned char)a7;
    ++idx;
  }
  return t;
}
constexpr PwTab PW = gen_powers();

// ---------------- helpers ----------------
DEV unsigned int f2bf(float f) {            // RNE float -> bf16 bits (prep path)
  unsigned int u = __builtin_bit_cast(unsigned int, f);
  u += 0x7fffu + ((u >> 16) & 1u);
  return u >> 16;
}
DEV unsigned int pack2_bits(float lo, float hi) { return f2bf(lo) | (f2bf(hi) << 16); }
// single-instruction packed conversion (gen hot path)
DEV unsigned int pack2(float lo, float hi) {
  unsigned int r;
  asm("v_cvt_pk_bf16_f32 %0, %1, %2" : "=v"(r) : "v"(lo), "v"(hi));
  return r;
}
DEV float softplusf(float x) { return (x > 20.f) ? x : log1pf(expf(x)); }

// ---- monomial evaluation: ALL table indices are template params (scratch-proof) ----
template<int JJ, int C>
DEV void mono_step(float& r, float& i,
                   const float (&lx)[8][3], const float (&ly)[8][3]) {
  constexpr int pc = PW.a[JJ].p[C];
  if constexpr (pc > 0) {
    const float ar = lx[C][pc-1], ai = ly[C][pc-1];
    const float tr = r*ar - i*ai;
    i = r*ai + i*ar;
    r = tr;
  }
}
template<int JJ>
DEV void mono_eval(float& mr, float& mi,
                   const float (&lx)[8][3], const float (&ly)[8][3]) {
  float r = 1.f, i = 0.f;
  mono_step<JJ,0>(r,i,lx,ly); mono_step<JJ,1>(r,i,lx,ly);
  mono_step<JJ,2>(r,i,lx,ly); mono_step<JJ,3>(r,i,lx,ly);
  mono_step<JJ,4>(r,i,lx,ly); mono_step<JJ,5>(r,i,lx,ly);
  mono_step<JJ,6>(r,i,lx,ly); mono_step<JJ,7>(r,i,lx,ly);
  mr = r; mi = i;
}
template<int JJ>
DEV void mono_eval_guard(float& r, float& i,
                         const float (&lx)[8][3], const float (&ly)[8][3]) {
  if constexpr (JJ < KM) mono_eval<JJ>(r, i, lx, ly);
  else { r = 0.f; i = 0.f; }
}

// ---- gen: chunk T covers monomials [8T, 8T+8) = k-slice (ks=T>>2, g=T&3) ----
template<int T, int... Us>
DEV void gen8(std::integer_sequence<int, Us...>, float (&mr)[8], float (&mi)[8],
              const float (&lx)[8][3], const float (&ly)[8][3]) {
  (mono_eval_guard<8*T + Us>(mr[Us], mi[Us], lx, ly), ...);
}
template<int T>
DEV void gen_chunk(const float (&lx)[8][3], const float (&ly)[8][3],
                   unsigned int* Xf, unsigned int* Yf, int mf, int r15) {
  constexpr int ksv = T >> 2;
  constexpr int gv  = T & 3;
  float mr[8], mi[8];
  gen8<T>(std::make_integer_sequence<int, 8>{}, mr, mi, lx, ly);
  uint4 ux, uy;
  ux.x = pack2(mr[0], mr[1]); ux.y = pack2(mr[2], mr[3]);
  ux.z = pack2(mr[4], mr[5]); ux.w = pack2(mr[6], mr[7]);
  uy.x = pack2(mi[0], mi[1]); uy.y = pack2(mi[2], mi[3]);
  uy.z = pack2(mi[4], mi[5]); uy.w = pack2(mi[6], mi[7]);
  const unsigned int off = (unsigned int)((mf*6 + ksv)*256 + gv*64 + r15*4);
  *(uint4*)&Xf[off] = ux;
  *(uint4*)&Yf[off] = uy;
}
template<int W, int... Ts>
DEV void gen_seq(std::integer_sequence<int, Ts...>,
                 const float (&lx)[8][3], const float (&ly)[8][3],
                 unsigned int* Xf, unsigned int* Yf, int mf, int r15) {
  (gen_chunk<6*W + Ts>(lx, ly, Xf, Yf, mf, r15), ...);
}
template<int W>
DEV void gen_wave(const float (&lx)[8][3], const float (&ly)[8][3],
                  unsigned int* Xf, unsigned int* Yf, int mf, int r15) {
  gen_seq<W>(std::make_integer_sequence<int, 6>{}, lx, ly, Xf, Yf, mf, r15);
}

// ---------------- prep: conj(L)^T -> bf16 B-operand fragments (triangular) ----------
__global__ void __launch_bounds__(256) poskahler_prep(
    const float* __restrict__ Lre, const float* __restrict__ Lim,
    uint4* __restrict__ bp, uint4* __restrict__ bq) {
  const int tid = blockIdx.x * 256 + threadIdx.x;
  if (tid >= NB) return;
  const int lane = tid & 63;
  const int it = (tid >> 6) / KS;
  const int ks = (tid >> 6) % KS;
  const int j  = it * 16 + (lane & 15);
  const int ib = ks * 32 + ((lane >> 4) << 3);
  float pr[8], qr[8];
#pragma unroll
  for (int e = 0; e < 8; ++e) { pr[e] = 0.f; qr[e] = 0.f; }
  if (j < KM) {
#pragma unroll
    for (int e = 0; e < 8; ++e) {
      const int i = ib + e;
      if (i < KM) {
        if (i > j)      { pr[e] = Lre[i*KM + j]; qr[e] = -Lim[i*KM + j]; }
        else if (i == j){ pr[e] = softplusf(Lre[j*KM + j]) + 0.001f; }
      }
    }
  }
  uint4 up, uq;
  up.x = pack2_bits(pr[0], pr[1]); up.y = pack2_bits(pr[2], pr[3]);
  up.z = pack2_bits(pr[4], pr[5]); up.w = pack2_bits(pr[6], pr[7]);
  uq.x = pack2_bits(qr[0], qr[1]); uq.y = pack2_bits(qr[2], qr[3]);
  uq.z = pack2_bits(qr[4], qr[5]); uq.w = pack2_bits(qr[6], qr[7]);
  bp[tid] = up;
  bq[tid] = uq;
}

// ---------------- main k-loop building blocks (fully static) ----------------
template<int KSv>
DEV void load_tiles(const uint4* __restrict__ bp, const uint4* __restrict__ bq,
                    int wv, int lane, uint4 (&tp)[3], uint4 (&tq)[3]) {
#pragma unroll
  for (int ii = 0; ii < 3; ++ii) {
    const int it = 4*ii + wv;
    if (it <= 2*KSv + 1 && it < IT) {
      const int fs = (it*KS + KSv)*64 + lane;
      tp[ii] = bp[fs];
      tq[ii] = bq[fs];
    }
  }
}

template<int KSv>
DEV void compute_ks(const unsigned int* Xf, const unsigned int* Yf,
                    int wv, int lane,
                    const uint4 (&tp)[3], const uint4 (&tq)[3],
                    float (&aRe)[3][4][4], float (&aIm)[3][4][4]) {
  bf16x8 xf[4], yf[4];
#pragma unroll
  for (int mf = 0; mf < 4; ++mf) {
    const unsigned int off = (unsigned int)((mf*6 + KSv)*256) + (unsigned int)lane*4;
    xf[mf] = __builtin_bit_cast(bf16x8, *(const uint4*)&Xf[off]);
    yf[mf] = __builtin_bit_cast(bf16x8, *(const uint4*)&Yf[off]);
  }
#pragma unroll
  for (int ii = 0; ii < 3; ++ii) {
    const int it = 4*ii + wv;
    if (it <= 2*KSv + 1 && it < IT) {
      const uint4 up = tp[ii];
      const uint4 uq = tq[ii];
      uint4 un;
      un.x = uq.x ^ 0x80008000u; un.y = uq.y ^ 0x80008000u;
      un.z = uq.z ^ 0x80008000u; un.w = uq.w ^ 0x80008000u;
      const bf16x8 vp = __builtin_bit_cast(bf16x8, up);
      const bf16x8 vq = __builtin_bit_cast(bf16x8, uq);
      const bf16x8 vn = __builtin_bit_cast(bf16x8, un);
#pragma unroll
      for (int mf = 0; mf < 4; ++mf) {
        f32x4 cre = { aRe[ii][mf][0], aRe[ii][mf][1], aRe[ii][mf][2], aRe[ii][mf][3] };
        f32x4 cim = { aIm[ii][mf][0], aIm[ii][mf][1], aIm[ii][mf][2], aIm[ii][mf][3] };
        // wre = P x + Q y ; wim = P y - Q x
        cre = __builtin_amdgcn_mfma_f32_16x16x32_bf16(xf[mf], vp, cre, 0, 0, 0);
        cre = __builtin_amdgcn_mfma_f32_16x16x32_bf16(yf[mf], vq, cre, 0, 0, 0);
        cim = __builtin_amdgcn_mfma_f32_16x16x32_bf16(yf[mf], vp, cim, 0, 0, 0);
        cim = __builtin_amdgcn_mfma_f32_16x16x32_bf16(xf[mf], vn, cim, 0, 0, 0);
#pragma unroll
        for (int rr = 0; rr < 4; ++rr) { aRe[ii][mf][rr] = cre[rr]; aIm[ii][mf][rr] = cim[rr]; }
      }
    }
  }
}

// ---------------- main: monomials -> w = L^H z via MFMA -> log(|w|^2) --------------
__global__ void __launch_bounds__(256, 2) poskahler_main(
    const float* __restrict__ q,
    const uint4* __restrict__ bp, const uint4* __restrict__ bq,
    float* __restrict__ out) {
  // fragment-ordered monomial store: region (mf*6+ks)*256 dwords, lane entry lane*4
  __shared__ __align__(16) unsigned int Xf[6144];
  __shared__ __align__(16) unsigned int Yf[6144];
  __shared__ float qpart[4][ROWS];

  const int t     = threadIdx.x;
  const int lane  = t & 63;
  const int wv    = t >> 6;                 // 4 waves
  const int bbase = blockIdx.x * ROWS;
  const int mf_r  = lane >> 4;              // gen: this thread's row -> frag mf
  const int r15   = lane & 15;

  // ---- q row load FIRST (HBM latency starts draining before everything else) ----
  const float* qr = q + (size_t)(bbase + lane) * 16;
  const float4 q0 = ((const float4*)qr)[0];
  const float4 q1 = ((const float4*)qr)[1];
  const float4 q2 = ((const float4*)qr)[2];
  const float4 q3 = ((const float4*)qr)[3];

  // ---- B-tile prefetch for ks=0,1 (latency hides under gen phase) ----
  uint4 tpA[3] = {}, tqA[3] = {}, tpB[3] = {}, tqB[3] = {};
  load_tiles<0>(bp, bq, wv, lane, tpA, tqA);
  load_tiles<1>(bp, bq, wv, lane, tpB, tqB);

  // ---- monomial generation: wave wv covers monomials [48wv, 48wv+48) of each row --
  {
    const float xs[8] = {q0.x,q0.y,q0.z,q0.w,q1.x,q1.y,q1.z,q1.w};
    const float ys[8] = {q2.x,q2.y,q2.z,q2.w,q3.x,q3.y,q3.z,q3.w};
    float lx[8][3], ly[8][3];
#pragma unroll
    for (int c = 0; c < 8; ++c) {
      const float xr = xs[c], yi = ys[c];
      lx[c][0] = xr;             ly[c][0] = yi;
      lx[c][1] = xr*xr - yi*yi;  ly[c][1] = 2.f*xr*yi;
      lx[c][2] = lx[c][1]*xr - ly[c][1]*yi;
      ly[c][2] = lx[c][1]*yi + ly[c][1]*xr;
    }
    switch (wv) {
      case 0: gen_wave<0>(lx, ly, Xf, Yf, mf_r, r15); break;
      case 1: gen_wave<1>(lx, ly, Xf, Yf, mf_r, r15); break;
      case 2: gen_wave<2>(lx, ly, Xf, Yf, mf_r, r15); break;
      default: gen_wave<3>(lx, ly, Xf, Yf, mf_r, r15); break;
    }
  }
  __syncthreads();

  // ---- w = L^H z : ks fully unrolled, double-buffered B tiles ----
  float aRe[3][4][4], aIm[3][4][4];
#pragma unroll
  for (int ii = 0; ii < 3; ++ii)
#pragma unroll
    for (int mf = 0; mf < 4; ++mf)
#pragma unroll
      for (int rr = 0; rr < 4; ++rr) { aRe[ii][mf][rr] = 0.f; aIm[ii][mf][rr] = 0.f; }

  compute_ks<0>(Xf, Yf, wv, lane, tpA, tqA, aRe, aIm);
  load_tiles<2>(bp, bq, wv, lane, tpA, tqA);
  compute_ks<1>(Xf, Yf, wv, lane, tpB, tqB, aRe, aIm);
  load_tiles<3>(bp, bq, wv, lane, tpB, tqB);
  compute_ks<2>(Xf, Yf, wv, lane, tpA, tqA, aRe, aIm);
  load_tiles<4>(bp, bq, wv, lane, tpA, tqA);
  compute_ks<3>(Xf, Yf, wv, lane, tpB, tqB, aRe, aIm);
  load_tiles<5>(bp, bq, wv, lane, tpB, tqB);
  compute_ks<4>(Xf, Yf, wv, lane, tpA, tqA, aRe, aIm);
  compute_ks<5>(Xf, Yf, wv, lane, tpB, tqB, aRe, aIm);

  // ---- epilogue: quad partial = sum_j |w_j|^2 ----
  float p[4][4];
#pragma unroll
  for (int mf = 0; mf < 4; ++mf)
#pragma unroll
    for (int rr = 0; rr < 4; ++rr) p[mf][rr] = 0.f;

#pragma unroll
  for (int ii = 0; ii < 3; ++ii)
#pragma unroll
    for (int mf = 0; mf < 4; ++mf)
#pragma unroll
      for (int rr = 0; rr < 4; ++rr)
        p[mf][rr] += aRe[ii][mf][rr]*aRe[ii][mf][rr] + aIm[ii][mf][rr]*aIm[ii][mf][rr];

#pragma unroll
  for (int mf = 0; mf < 4; ++mf)
#pragma unroll
    for (int rr = 0; rr < 4; ++rr) {
      float v = p[mf][rr];
      v += __shfl_xor(v, 1);
      v += __shfl_xor(v, 2);
      v += __shfl_xor(v, 4);
      v += __shfl_xor(v, 8);
      p[mf][rr] = v;
    }

  if (r15 == 0) {
    const int g = lane >> 4;
#pragma unroll
    for (int mf = 0; mf < 4; ++mf)
#pragma unroll
      for (int rr = 0; rr < 4; ++rr)
        qpart[wv][mf*16 + 4*g + rr] = p[mf][rr];
  }
  __syncthreads();
  if (t < ROWS) {
    const float quad = qpart[0][t] + qpart[1][t] + qpart[2][t] + qpart[3][t];
    out[bbase + t] = logf(quad + 1e-12f);
  }
}

// ---------------- host ----------------
extern "C" void kernel_launch(void* const* d_in, const int* in_sizes, int n_in,
                              void* d_out, int out_size, void* d_ws, size_t ws_size,
                              hipStream_t stream) {
  const float* q   = (const float*)d_in[0];
  const float* Lre = (const float*)d_in[1];
  const float* Lim = (const float*)d_in[2];
  float* out = (float*)d_out;
  uint4* bp = (uint4*)d_ws;
  uint4* bq = bp + NB;
  const int B = in_sizes[0] / 16;
  poskahler_prep<<<(NB + 255)/256, 256, 0, stream>>>(Lre, Lim, bp, bq);
  poskahler_main<<<B / ROWS, 256, 0, stream>>>(q, bp, bq, out);
}